// Round 5
// baseline (306.150 us; speedup 1.0000x reference)
//
#include <hip/hip_runtime.h>
#include <hip/hip_bf16.h>
#include <hip/hip_fp8.h>

typedef __bf16 bf16_t;
typedef bf16_t bf16x4 __attribute__((ext_vector_type(4)));
typedef bf16_t bf16x8 __attribute__((ext_vector_type(8)));
typedef float  f32x4  __attribute__((ext_vector_type(4)));

#define B_  8
#define L_  2048
#define H_  1024
#define LV_ 256

typedef const __attribute__((address_space(1))) void* gptr_as1;
typedef __attribute__((address_space(3))) void* lptr_as3;

__device__ __forceinline__ void gload_lds16(void* lds_base, const void* gsrc) {
  __builtin_amdgcn_global_load_lds((gptr_as1)gsrc, (lptr_as3)lds_base, 16, 0, 0);
}

__device__ __forceinline__ unsigned char to_fp8(float x) {
  return __hip_fp8_e4m3(x).__x;
}

// ---- vision mean-pool: 64 blocks, 2-way k-split, LDS combine ---------------
__global__ __launch_bounds__(256) void vpool64(const float* __restrict__ vf,
                                               float* __restrict__ pooled) {
  __shared__ float part[256];
  int bid = blockIdx.x;                 // b(8) x hc(8)
  int b = bid >> 3, hc = bid & 7;
  int t = threadIdx.x;
  int h = hc * 128 + (t & 127);
  int kh = t >> 7;
  const float* p = vf + (long)b * (LV_ * H_) + (long)kh * 128 * H_ + h;
  float s = 0.f;
  #pragma unroll 4
  for (int k = 0; k < 128; ++k) s += p[k * H_];
  part[t] = s;
  __syncthreads();
  if (t < 128)
    pooled[b * H_ + hc * 128 + t] = (part[t] + part[t + 128]) * (1.f / 256.f);
}

// ------- out[b][o] = sum_h x[b][h]*W[o*ldw+woff+h] (+bias), 8 batches ------
__global__ void matvec8(const float* __restrict__ W, int ldw, int woff,
                        const float* __restrict__ x,
                        const float* __restrict__ bias,
                        float* __restrict__ out) {
  int wid = threadIdx.x >> 6, lane = threadIdx.x & 63;
  int o = blockIdx.x * 4 + wid;
  const float* wr = W + (long)o * ldw + woff;
  float acc[B_];
  #pragma unroll
  for (int b = 0; b < B_; ++b) acc[b] = 0.f;
  for (int j = 0; j < 16; ++j) {
    float w = wr[lane + 64 * j];
    #pragma unroll
    for (int b = 0; b < B_; ++b) acc[b] += w * x[b * H_ + lane + 64 * j];
  }
  #pragma unroll
  for (int b = 0; b < B_; ++b)
    for (int off = 32; off; off >>= 1) acc[b] += __shfl_down(acc[b], off);
  if (lane == 0) {
    float bb = bias ? bias[o] : 0.f;
    #pragma unroll
    for (int b = 0; b < B_; ++b) out[b * H_ + o] = acc[b] + bb;
  }
}

// ---- fused small ops (all read-only on vp): 768 blocks ---------------------
__global__ __launch_bounds__(256) void smallops(const float* __restrict__ Wg,
                                                const float* __restrict__ Wt,
                                                const float* __restrict__ vp,
                                                const float* __restrict__ bt,
                                                const float* __restrict__ bg,
                                                float* __restrict__ gv,
                                                float* __restrict__ partU,
                                                float* __restrict__ cbb) {
  int bid = blockIdx.x;
  if (bid < 256) {
    int wid = threadIdx.x >> 6, lane = threadIdx.x & 63;
    int o = bid * 4 + wid;
    const float* wr = Wg + (long)o * 2048 + 1024;
    float acc[B_];
    #pragma unroll
    for (int b = 0; b < B_; ++b) acc[b] = 0.f;
    for (int j = 0; j < 16; ++j) {
      float w = wr[lane + 64 * j];
      #pragma unroll
      for (int b = 0; b < B_; ++b) acc[b] += w * vp[b * H_ + lane + 64 * j];
    }
    #pragma unroll
    for (int b = 0; b < B_; ++b)
      for (int off = 32; off; off >>= 1) acc[b] += __shfl_down(acc[b], off);
    if (lane == 0) {
      #pragma unroll
      for (int b = 0; b < B_; ++b) gv[b * H_ + o] = acc[b];
    }
  } else if (bid < 512) {
    int lb = bid - 256;                 // eb(4) x oc(64)
    int e = (lb & 3) * 256 + threadIdx.x;
    int oc = lb >> 2;
    float a[B_];
    #pragma unroll
    for (int b = 0; b < B_; ++b) a[b] = 0.f;
    #pragma unroll
    for (int i = 0; i < 16; ++i) {
      int o = oc * 16 + i;
      float w = Wt[(long)o * H_ + e];
      #pragma unroll
      for (int b = 0; b < B_; ++b) a[b] += w * vp[b * H_ + o];
    }
    #pragma unroll
    for (int b = 0; b < B_; ++b) partU[oc * 8192 + b * 1024 + e] = a[b];
  } else {
    int lb = bid - 512;
    int wid = threadIdx.x >> 6, lane = threadIdx.x & 63;
    int o = lb * 4 + wid;
    const float* wr = Wg + (long)o * 2048;
    float acc = 0.f;
    for (int j = 0; j < 16; ++j) acc += wr[lane + 64 * j] * bt[lane + 64 * j];
    for (int off = 32; off; off >>= 1) acc += __shfl_down(acc, off);
    if (lane == 0) cbb[o] = acc + bg[o];
  }
}

// ---- dst[j] = scale * sum_{c<nc} src[c*8192 + j], j < 8192 ----------------
__global__ __launch_bounds__(256) void reduceK(const float* __restrict__ src,
                                               float* __restrict__ dst,
                                               int nc, float scale) {
  int j = blockIdx.x * 256 + threadIdx.x;
  float s = 0.f;
  for (int c = 0; c < nc; ++c) s += src[c * 8192 + j];
  dst[j] = s * scale;
}

// ---- merged: [0,1024) text -> fp8 FRAG-PACKED + agreement dot;
//      [1024,1280) Wt transpose-convert -----------------------------------
// Packed layout: chunk(mb,kb) @ (mb*32+kb)*512; lane l byte j holds
// fp8(text[mb*16 + (l&15)][kb*32 + (l>>4)*8 + j]) -- exact MFMA A/B operand
// order for 16x16x32 fp8.
__global__ __launch_bounds__(256) void cvt_pack(const float* __restrict__ text,
                                                const float* __restrict__ u,
                                                const float* __restrict__ Wt,
                                                unsigned char* __restrict__ t8p,
                                                float* __restrict__ agr,
                                                bf16_t* __restrict__ WtT) {
  int bid = blockIdx.x;
  int t = threadIdx.x;
  if (bid < 1024) {
    __shared__ unsigned char q8[16][1032];   // +8B row pad: frag-read conflicts <=4-way
    __shared__ float dred[4][16];
    int b = bid >> 7;                        // 128 blocks per batch
    int wid = t >> 6, lane = t & 63;
    const float4* trow = (const float4*)(text + (long)bid * (16 * H_));
    float4 uu = ((const float4*)(u + b * H_))[t];
    #pragma unroll 4
    for (int i = 0; i < 16; ++i) {           // i = row within 16-row block
      float4 v = trow[i * 256 + t];          // coalesced
      float d = v.x * uu.x + v.y * uu.y + v.z * uu.z + v.w * uu.w;
      for (int off = 32; off; off >>= 1) d += __shfl_down(d, off);
      if (!lane) dred[wid][i] = d;
      uchar4 q = { to_fp8(v.x), to_fp8(v.y), to_fp8(v.z), to_fp8(v.w) };
      *(uchar4*)&q8[i][t * 4] = q;
    }
    __syncthreads();
    if (t < 16)
      agr[bid * 16 + t] = dred[0][t] + dred[1][t] + dred[2][t] + dred[3][t];
    unsigned char* dst = t8p + (long)bid * 16384;   // 32 chunks x 512B
    #pragma unroll
    for (int c = 0; c < 8; ++c) {
      int kb = wid * 8 + c;
      uint2 r = *(const uint2*)&q8[lane & 15][kb * 32 + (lane >> 4) * 8];
      *(uint2*)(dst + kb * 512 + lane * 8) = r;     // coalesced 512B/wave
    }
  } else {
    __shared__ float tile[64][65];
    int lb = bid - 1024;
    int hr = (lb >> 4) * 64;
    int ec = (lb & 15) * 64;
    int lr = t >> 4, lc = t & 15;
    #pragma unroll
    for (int rr = 0; rr < 4; ++rr) {
      int r = rr * 16 + lr;
      float4 v = *(const float4*)(Wt + (long)(hr + r) * H_ + ec + lc * 4);
      tile[r][lc * 4 + 0] = v.x; tile[r][lc * 4 + 1] = v.y;
      tile[r][lc * 4 + 2] = v.z; tile[r][lc * 4 + 3] = v.w;
    }
    __syncthreads();
    #pragma unroll
    for (int rr = 0; rr < 4; ++rr) {
      int er = rr * 16 + lr;
      bf16x4 o = { (bf16_t)tile[lc * 4 + 0][er], (bf16_t)tile[lc * 4 + 1][er],
                   (bf16_t)tile[lc * 4 + 2][er], (bf16_t)tile[lc * 4 + 3][er] };
      *(bf16x4*)(WtT + (long)(ec + er) * H_ + hr + lc * 4) = o;
    }
  }
}

// ---- merged: [0,256) Wc8p = frag-packed fp8(16 * Wgt@Wt); [256,264) softmax
__global__ __launch_bounds__(256) void wc_sm(const float* __restrict__ Wg,
                                             const bf16_t* __restrict__ Bt,
                                             unsigned char* __restrict__ Cw8,
                                             const float* __restrict__ ag,
                                             float* __restrict__ r) {
  __shared__ __align__(16) char lds[2][16384];
  __shared__ float red[4];
  if (blockIdx.x >= 256) {
    int b = blockIdx.x - 256, t = threadIdx.x;
    int wid = t >> 6, lane = t & 63;
    const float* a = ag + (long)b * L_;
    float v[8];
    float mx = -1e30f;
    #pragma unroll
    for (int j = 0; j < 8; ++j) { v[j] = 2.f * a[t + 256 * j]; mx = fmaxf(mx, v[j]); }
    for (int off = 32; off; off >>= 1) mx = fmaxf(mx, __shfl_down(mx, off));
    if (!lane) red[wid] = mx;
    __syncthreads();
    mx = fmaxf(fmaxf(red[0], red[1]), fmaxf(red[2], red[3]));
    __syncthreads();
    float sum = 0.f;
    #pragma unroll
    for (int j = 0; j < 8; ++j) { v[j] = __expf(v[j] - mx); sum += v[j]; }
    for (int off = 32; off; off >>= 1) sum += __shfl_down(sum, off);
    if (!lane) red[wid] = sum;
    __syncthreads();
    sum = red[0] + red[1] + red[2] + red[3];
    float inv = 1.f / sum;
    #pragma unroll
    for (int j = 0; j < 8; ++j) r[(long)b * L_ + t + 256 * j] = v[j] * inv;
    return;
  }
  const int tid = threadIdx.x;
  const int wid = tid >> 6, lane = tid & 63;
  const int fr = lane & 15, fkb = (lane >> 4) * 16, fq = (lane >> 4) * 4;
  const int wm = wid >> 1, wn = wid & 1;
  const int tm = blockIdx.x & 15, tn = blockIdx.x >> 4;
  const int m0 = tm * 64, n0 = tn * 64;

  const int d0 = tid * 16;
  const int p  = d0 ^ (((d0 >> 7) & 7) << 4);
  const int rS = p >> 7, cS = (p & 127) >> 1;

  const int swz = (fr & 7) << 4;
  const int e0 = fkb ^ swz;
  const int e1 = (64 + fkb) ^ swz;

  auto stage = [&](int t) {
    char* base = lds[t & 1];
    gload_lds16(base + 8192 + d0,        Bt + (long)(n0 + rS) * H_ + t * 64 + cS);
    gload_lds16(base + 8192 + 4096 + d0, Bt + (long)(n0 + 32 + rS) * H_ + t * 64 + cS);
    const float* a0 = Wg + (long)(m0 + rS) * 2048 + t * 64 + cS;
    const float* a1 = Wg + (long)(m0 + 32 + rS) * 2048 + t * 64 + cS;
    float4 x0 = *(const float4*)a0, x1 = *(const float4*)(a0 + 4);
    float4 y0 = *(const float4*)a1, y1 = *(const float4*)(a1 + 4);
    bf16x8 bx = { (bf16_t)x0.x, (bf16_t)x0.y, (bf16_t)x0.z, (bf16_t)x0.w,
                  (bf16_t)x1.x, (bf16_t)x1.y, (bf16_t)x1.z, (bf16_t)x1.w };
    bf16x8 by = { (bf16_t)y0.x, (bf16_t)y0.y, (bf16_t)y0.z, (bf16_t)y0.w,
                  (bf16_t)y1.x, (bf16_t)y1.y, (bf16_t)y1.z, (bf16_t)y1.w };
    *(bf16x8*)(base + d0) = bx;
    *(bf16x8*)(base + 4096 + d0) = by;
  };

  f32x4 acc[2][2];
  #pragma unroll
  for (int m = 0; m < 2; ++m)
    #pragma unroll
    for (int n = 0; n < 2; ++n) acc[m][n] = (f32x4){0.f, 0.f, 0.f, 0.f};

  stage(0);
  __syncthreads();
  for (int t = 0; t < 16; ++t) {
    if (t + 1 < 16) stage(t + 1);
    char* buf = lds[t & 1];
    char* AR = buf + (wm * 32 + fr) * 128;
    char* BR = buf + 8192 + (wn * 32 + fr) * 128;
    bf16x8 a[2][2], b[2][2];
    #pragma unroll
    for (int m = 0; m < 2; ++m) {
      a[m][0] = *(const bf16x8*)(AR + m * 2048 + e0);
      a[m][1] = *(const bf16x8*)(AR + m * 2048 + e1);
      b[m][0] = *(const bf16x8*)(BR + m * 2048 + e0);
      b[m][1] = *(const bf16x8*)(BR + m * 2048 + e1);
    }
    #pragma unroll
    for (int m = 0; m < 2; ++m)
      #pragma unroll
      for (int n = 0; n < 2; ++n) {
        acc[m][n] = __builtin_amdgcn_mfma_f32_16x16x32_bf16(a[m][0], b[n][0], acc[m][n], 0, 0, 0);
        acc[m][n] = __builtin_amdgcn_mfma_f32_16x16x32_bf16(a[m][1], b[n][1], acc[m][n], 0, 0, 0);
      }
    __syncthreads();
  }
  // frag-packed write: chunk(nb=row>>4, kb=col>>5), lane=(row&15)|(((col>>3)&3)<<4)
  #pragma unroll
  for (int m = 0; m < 2; ++m)
    #pragma unroll
    for (int r_ = 0; r_ < 4; ++r_) {
      int row = m0 + wm * 32 + m * 16 + fq + r_;
      #pragma unroll
      for (int n = 0; n < 2; ++n) {
        int col = n0 + wn * 32 + n * 16 + fr;
        Cw8[((row >> 4) * 32 + (col >> 5)) * 512
            + ((row & 15) + (((col >> 3) & 3) << 4)) * 8 + (col & 7)]
          = to_fp8(acc[m][n][r_] * 16.f);   // x16 into e4m3 normal range
      }
    }
}

// ====== full-row fp8 GEMM + gate/residual + LayerNorm, all in one ==========
// 512 blocks x 32 rows x 1024 cols, 512 thr (8 waves, each 32x128 out).
// 2 blocks/CU (LDS 66KB dyn, VGPR<=128): one block's memory epilogue overlaps
// the other's MFMA loop (m114). 32 kb-steps; per kb per wave: 4 B-gloads
// (+1 A-gload on wave0, issued FIRST so uniform vmcnt(4) is safe), 10
// ds_read_b64, 16 MFMA. Counted vmcnt(4) = next kb always in flight.
// Epilogue: dump acc->LDS (XOR swizzle a^=((a>>7)&7)<<4, two 16-row halves
// reusing B-buf), then fully-coalesced float4 gate/res/LN pass; stats via
// shfl_xor over the row's 32 lanes.
#define BOFF 16777216   // Wc8p offset from t8p base
__global__ __launch_bounds__(512, 4)
void gemm_ln(const unsigned char* __restrict__ AB,
             const float* __restrict__ textf,
             const float* __restrict__ cbb, const float* __restrict__ rbuf,
             const float* __restrict__ gvb, const float* __restrict__ vpb,
             const float* __restrict__ gamma, const float* __restrict__ beta,
             float* __restrict__ out) {
  extern __shared__ __align__(16) char dlds[];  // [0,65536) B dbuf, [65536,67584) A dbuf
  const int tid  = threadIdx.x;
  const int w    = tid >> 6;            // 0..7 col strip (128 cols)
  const int lane = tid & 63;
  const int fr   = lane & 15;
  const int fq   = (lane >> 4) * 4;
  const int bid  = blockIdx.x;
  const long m0  = (long)bid * 32;

  // B: chunk nb at BOFF + nb*16384 + kb*512; round r_ covers nb = r_*16+(tid>>5)
  const unsigned char* bSrc = AB + BOFF + (long)(tid >> 5) * 16384 + (tid & 31) * 16;
  const int bDst = tid * 16;
  // A: block's 32KB contiguous [bid*32768, +32768): mb half + kb*512
  const unsigned char* aSrc = AB + (long)bid * 32768 + (lane >> 5) * 16384 + (lane & 31) * 16;

  f32x4 acc[2][8];
  #pragma unroll
  for (int m = 0; m < 2; ++m)
    #pragma unroll
    for (int n = 0; n < 8; ++n) acc[m][n] = (f32x4){0.f, 0.f, 0.f, 0.f};

#define STAGE(p)                                                        \
  {                                                                     \
    if (w == 0)                                                         \
      gload_lds16(dlds + 65536 + ((p) & 1) * 1024 + lane * 16,          \
                  aSrc + (p) * 512);                                    \
    _Pragma("unroll")                                                   \
    for (int r_ = 0; r_ < 4; ++r_)                                      \
      gload_lds16(dlds + ((p) & 1) * 32768 + r_ * 8192 + bDst,          \
                  bSrc + (long)r_ * 262144 + (p) * 512);                \
  }
#define KITER(p, WN)                                                    \
  {                                                                     \
    asm volatile("s_waitcnt vmcnt(" #WN ")" ::: "memory");              \
    __builtin_amdgcn_s_barrier();                                       \
    const char* Ab_ = dlds + 65536 + ((p) & 1) * 1024 + lane * 8;       \
    const char* Bb_ = dlds + ((p) & 1) * 32768 + w * 4096 + lane * 8;   \
    long a_[2], b_[8];                                                  \
    a_[0] = *(const long*)(Ab_);                                        \
    a_[1] = *(const long*)(Ab_ + 512);                                  \
    _Pragma("unroll")                                                   \
    for (int n_ = 0; n_ < 8; ++n_)                                      \
      b_[n_] = *(const long*)(Bb_ + n_ * 512);                          \
    asm volatile("s_waitcnt lgkmcnt(0)" ::: "memory");                  \
    __builtin_amdgcn_sched_barrier(0);                                  \
    __builtin_amdgcn_s_barrier();                                       \
    if ((p) + 2 < 32) STAGE((p) + 2)                                    \
    __builtin_amdgcn_s_setprio(1);                                      \
    _Pragma("unroll")                                                   \
    for (int m_ = 0; m_ < 2; ++m_)                                      \
      _Pragma("unroll")                                                 \
      for (int n_ = 0; n_ < 8; ++n_)                                    \
        acc[m_][n_] = __builtin_amdgcn_mfma_f32_16x16x32_fp8_fp8(       \
            a_[m_], b_[n_], acc[m_][n_], 0, 0, 0);                      \
    __builtin_amdgcn_s_setprio(0);                                      \
  }

  STAGE(0)
  asm volatile("" ::: "memory");
  STAGE(1)

  #pragma unroll
  for (int p = 0; p < 31; ++p) KITER(p, 4)
  KITER(31, 0)
#undef KITER
#undef STAGE

  // ---- epilogue: coalesced gate+res+LN via LDS transpose, 2 halves --------
  const int bat = (int)(m0 >> 11);
  const float* gvr = gvb + bat * H_;
  const float* vpr = vpb + bat * H_;
  const int row16 = tid >> 5;
  const int j     = tid & 31;

  #pragma unroll
  for (int h = 0; h < 2; ++h) {
    __syncthreads();
    // dump acc[h] (raw GEMM sums) to LDS at [row16][col], XOR-swizzled
    #pragma unroll
    for (int n = 0; n < 8; ++n) {
      #pragma unroll
      for (int r = 0; r < 4; ++r) {
        int a = (fq + r) * 4096 + (w * 128 + n * 16 + fr) * 4;
        a ^= ((a >> 7) & 7) << 4;
        *(float*)(dlds + a) = acc[h][n][r];
      }
    }
    __syncthreads();
    long row = m0 + h * 16 + row16;
    float rv = rbuf[row];
    const float* tf = textf + row * H_;
    float fv[32];
    float s = 0.f, q = 0.f;
    #pragma unroll
    for (int k = 0; k < 8; ++k) {
      int c0 = j * 32 + k * 4;
      int a = row16 * 4096 + c0 * 4;
      a ^= ((a >> 7) & 7) << 4;
      f32x4 g4 = *(const f32x4*)(dlds + a);
      float4 t4  = *(const float4*)(tf + c0);
      float4 cb4 = *(const float4*)(cbb + c0);
      float4 gv4 = *(const float4*)(gvr + c0);
      float4 vp4 = *(const float4*)(vpr + c0);
      float gp, g, f;
      gp = g4[0] * 0.0625f + cb4.x + rv * gv4.x;
      g = 1.f / (1.f + __expf(-gp));
      f = t4.x + g * rv * vp4.x; fv[k * 4 + 0] = f; s += f; q += f * f;
      gp = g4[1] * 0.0625f + cb4.y + rv * gv4.y;
      g = 1.f / (1.f + __expf(-gp));
      f = t4.y + g * rv * vp4.y; fv[k * 4 + 1] = f; s += f; q += f * f;
      gp = g4[2] * 0.0625f + cb4.z + rv * gv4.z;
      g = 1.f / (1.f + __expf(-gp));
      f = t4.z + g * rv * vp4.z; fv[k * 4 + 2] = f; s += f; q += f * f;
      gp = g4[3] * 0.0625f + cb4.w + rv * gv4.w;
      g = 1.f / (1.f + __expf(-gp));
      f = t4.w + g * rv * vp4.w; fv[k * 4 + 3] = f; s += f; q += f * f;
    }
    #pragma unroll
    for (int off = 1; off < 32; off <<= 1) {   // reduce over the row's 32 lanes
      s += __shfl_xor(s, off);
      q += __shfl_xor(q, off);
    }
    float mu  = s * (1.f / H_);
    float var = q * (1.f / H_) - mu * mu;
    float inv = rsqrtf(var + 1e-5f);
    float* op = out + row * H_;
    #pragma unroll
    for (int k = 0; k < 8; ++k) {
      int c0 = j * 32 + k * 4;
      float4 gg = *(const float4*)(gamma + c0);
      float4 bb = *(const float4*)(beta + c0);
      float4 o4;
      o4.x = (fv[k * 4 + 0] - mu) * inv * gg.x + bb.x;
      o4.y = (fv[k * 4 + 1] - mu) * inv * gg.y + bb.y;
      o4.z = (fv[k * 4 + 2] - mu) * inv * gg.z + bb.z;
      o4.w = (fv[k * 4 + 3] - mu) * inv * gg.w + bb.w;
      *(float4*)(op + c0) = o4;
    }
  }
}

extern "C" void kernel_launch(void* const* d_in, const int* in_sizes, int n_in,
                              void* d_out, int out_size, void* d_ws, size_t ws_size,
                              hipStream_t stream) {
  const float* text  = (const float*)d_in[0];
  const float* vis   = (const float*)d_in[1];
  const float* Wt    = (const float*)d_in[2];
  const float* bt    = (const float*)d_in[3];
  const float* Wv    = (const float*)d_in[4];
  const float* bv    = (const float*)d_in[5];
  const float* Wg    = (const float*)d_in[6];
  const float* bg    = (const float*)d_in[7];
  const float* gamma = (const float*)d_in[8];
  const float* beta  = (const float*)d_in[9];
  float* out = (float*)d_out;

  char* ws = (char*)d_ws;
  unsigned char* t8p   = (unsigned char*)(ws);                    // 16 MiB (packed A)
  unsigned char* Wc8p  = (unsigned char*)(ws + (size_t)16777216); // 1 MiB (packed B)
  bf16_t* WtT_b = (bf16_t*)(ws + (size_t)17825792);               // 2 MiB
  float*  pooled = (float*)(ws + (size_t)19922944);               // 32 KiB
  float*  vp     = (float*)(ws + (size_t)19955712);               // 32 KiB
  float*  gv     = (float*)(ws + (size_t)19988480);               // 32 KiB
  float*  u      = (float*)(ws + (size_t)20021248);               // 32 KiB
  float*  cbb    = (float*)(ws + (size_t)20054016);               // 4 KiB
  float*  rbuf   = (float*)(ws + (size_t)20058112);               // 64 KiB
  float*  agr    = (float*)(ws + (size_t)20123648);               // 64 KiB
  float*  partU  = (float*)(ws + (size_t)20189184);               // 2 MiB

  static bool smem_set = false;
  if (!smem_set) {
    (void)hipFuncSetAttribute((const void*)gemm_ln,
                              hipFuncAttributeMaxDynamicSharedMemorySize, 67584);
    smem_set = true;
  }

  vpool64<<<64, 256, 0, stream>>>(vis, pooled);                   // mean-pool
  matvec8<<<256, 256, 0, stream>>>(Wv, 1024, 0, pooled, bv, vp);  // vp
  smallops<<<768, 256, 0, stream>>>(Wg, Wt, vp, bt, bg, gv, partU, cbb);
  reduceK<<<32, 256, 0, stream>>>(partU, u, 64, 1.f);             // u = Wt^T vp

  cvt_pack<<<1280, 256, 0, stream>>>(text, u, Wt, t8p, agr, WtT_b);
  wc_sm<<<264, 256, 0, stream>>>(Wg, WtT_b, Wc8p, agr, rbuf);     // Wc8p + softmax

  gemm_ln<<<512, 512, 67584, stream>>>(t8p, text, cbb, rbuf, gv, vp,
                                       gamma, beta, out);
}

// Round 6
// 125.213 us; speedup vs baseline: 2.4450x; 2.4450x over previous
//
#include <hip/hip_runtime.h>
#include <hip/hip_bf16.h>
#include <hip/hip_fp8.h>

typedef __bf16 bf16_t;
typedef bf16_t bf16x4 __attribute__((ext_vector_type(4)));
typedef bf16_t bf16x8 __attribute__((ext_vector_type(8)));
typedef float  f32x4  __attribute__((ext_vector_type(4)));

#define B_  8
#define L_  2048
#define H_  1024
#define LV_ 256

typedef const __attribute__((address_space(1))) void* gptr_as1;
typedef __attribute__((address_space(3))) void* lptr_as3;

__device__ __forceinline__ void gload_lds16(void* lds_base, const void* gsrc) {
  __builtin_amdgcn_global_load_lds((gptr_as1)gsrc, (lptr_as3)lds_base, 16, 0, 0);
}
__device__ __forceinline__ void gload_lds4(void* lds_base, const void* gsrc) {
  __builtin_amdgcn_global_load_lds((gptr_as1)gsrc, (lptr_as3)lds_base, 4, 0, 0);
}

__device__ __forceinline__ unsigned char to_fp8(float x) {
  return __hip_fp8_e4m3(x).__x;
}

// ---- vision mean-pool: 64 blocks, 2-way k-split, LDS combine ---------------
__global__ __launch_bounds__(256) void vpool64(const float* __restrict__ vf,
                                               float* __restrict__ pooled) {
  __shared__ float part[256];
  int bid = blockIdx.x;                 // b(8) x hc(8)
  int b = bid >> 3, hc = bid & 7;
  int t = threadIdx.x;
  int h = hc * 128 + (t & 127);
  int kh = t >> 7;
  const float* p = vf + (long)b * (LV_ * H_) + (long)kh * 128 * H_ + h;
  float s = 0.f;
  #pragma unroll 4
  for (int k = 0; k < 128; ++k) s += p[k * H_];
  part[t] = s;
  __syncthreads();
  if (t < 128)
    pooled[b * H_ + hc * 128 + t] = (part[t] + part[t + 128]) * (1.f / 256.f);
}

// ------- out[b][o] = sum_h x[b][h]*W[o*ldw+woff+h] (+bias), 8 batches ------
__global__ void matvec8(const float* __restrict__ W, int ldw, int woff,
                        const float* __restrict__ x,
                        const float* __restrict__ bias,
                        float* __restrict__ out) {
  int wid = threadIdx.x >> 6, lane = threadIdx.x & 63;
  int o = blockIdx.x * 4 + wid;
  const float* wr = W + (long)o * ldw + woff;
  float acc[B_];
  #pragma unroll
  for (int b = 0; b < B_; ++b) acc[b] = 0.f;
  for (int j = 0; j < 16; ++j) {
    float w = wr[lane + 64 * j];
    #pragma unroll
    for (int b = 0; b < B_; ++b) acc[b] += w * x[b * H_ + lane + 64 * j];
  }
  #pragma unroll
  for (int b = 0; b < B_; ++b)
    for (int off = 32; off; off >>= 1) acc[b] += __shfl_down(acc[b], off);
  if (lane == 0) {
    float bb = bias ? bias[o] : 0.f;
    #pragma unroll
    for (int b = 0; b < B_; ++b) out[b * H_ + o] = acc[b] + bb;
  }
}

// ---- fused small ops (all read-only on vp): 768 blocks ---------------------
__global__ __launch_bounds__(256) void smallops(const float* __restrict__ Wg,
                                                const float* __restrict__ Wt,
                                                const float* __restrict__ vp,
                                                const float* __restrict__ bt,
                                                const float* __restrict__ bg,
                                                float* __restrict__ gv,
                                                float* __restrict__ partU,
                                                float* __restrict__ cbb) {
  int bid = blockIdx.x;
  if (bid < 256) {
    int wid = threadIdx.x >> 6, lane = threadIdx.x & 63;
    int o = bid * 4 + wid;
    const float* wr = Wg + (long)o * 2048 + 1024;
    float acc[B_];
    #pragma unroll
    for (int b = 0; b < B_; ++b) acc[b] = 0.f;
    for (int j = 0; j < 16; ++j) {
      float w = wr[lane + 64 * j];
      #pragma unroll
      for (int b = 0; b < B_; ++b) acc[b] += w * vp[b * H_ + lane + 64 * j];
    }
    #pragma unroll
    for (int b = 0; b < B_; ++b)
      for (int off = 32; off; off >>= 1) acc[b] += __shfl_down(acc[b], off);
    if (lane == 0) {
      #pragma unroll
      for (int b = 0; b < B_; ++b) gv[b * H_ + o] = acc[b];
    }
  } else if (bid < 512) {
    int lb = bid - 256;                 // eb(4) x oc(64)
    int e = (lb & 3) * 256 + threadIdx.x;
    int oc = lb >> 2;
    float a[B_];
    #pragma unroll
    for (int b = 0; b < B_; ++b) a[b] = 0.f;
    #pragma unroll
    for (int i = 0; i < 16; ++i) {
      int o = oc * 16 + i;
      float w = Wt[(long)o * H_ + e];
      #pragma unroll
      for (int b = 0; b < B_; ++b) a[b] += w * vp[b * H_ + o];
    }
    #pragma unroll
    for (int b = 0; b < B_; ++b) partU[oc * 8192 + b * 1024 + e] = a[b];
  } else {
    int lb = bid - 512;
    int wid = threadIdx.x >> 6, lane = threadIdx.x & 63;
    int o = lb * 4 + wid;
    const float* wr = Wg + (long)o * 2048;
    float acc = 0.f;
    for (int j = 0; j < 16; ++j) acc += wr[lane + 64 * j] * bt[lane + 64 * j];
    for (int off = 32; off; off >>= 1) acc += __shfl_down(acc, off);
    if (lane == 0) cbb[o] = acc + bg[o];
  }
}

// ---- dst[j] = scale * sum_{c<nc} src[c*8192 + j], j < 8192 ----------------
__global__ __launch_bounds__(256) void reduceK(const float* __restrict__ src,
                                               float* __restrict__ dst,
                                               int nc, float scale) {
  int j = blockIdx.x * 256 + threadIdx.x;
  float s = 0.f;
  for (int c = 0; c < nc; ++c) s += src[c * 8192 + j];
  dst[j] = s * scale;
}

// ---- merged: [0,1024) text -> fp8 FRAG-PACKED + agreement dot;
//      [1024,1280) Wt transpose-convert -----------------------------------
// Packed layout: chunk(mb,kb) @ (mb*32+kb)*512; lane l byte j holds
// fp8(text[mb*16 + (l&15)][kb*32 + (l>>4)*8 + j]) -- exact MFMA A/B operand
// order for 16x16x32 fp8.
__global__ __launch_bounds__(256) void cvt_pack(const float* __restrict__ text,
                                                const float* __restrict__ u,
                                                const float* __restrict__ Wt,
                                                unsigned char* __restrict__ t8p,
                                                float* __restrict__ agr,
                                                bf16_t* __restrict__ WtT) {
  int bid = blockIdx.x;
  int t = threadIdx.x;
  if (bid < 1024) {
    __shared__ unsigned char q8[16][1032];   // +8B row pad: frag-read conflicts <=4-way
    __shared__ float dred[4][16];
    int b = bid >> 7;                        // 128 blocks per batch
    int wid = t >> 6, lane = t & 63;
    const float4* trow = (const float4*)(text + (long)bid * (16 * H_));
    float4 uu = ((const float4*)(u + b * H_))[t];
    #pragma unroll 4
    for (int i = 0; i < 16; ++i) {           // i = row within 16-row block
      float4 v = trow[i * 256 + t];          // coalesced
      float d = v.x * uu.x + v.y * uu.y + v.z * uu.z + v.w * uu.w;
      for (int off = 32; off; off >>= 1) d += __shfl_down(d, off);
      if (!lane) dred[wid][i] = d;
      uchar4 q = { to_fp8(v.x), to_fp8(v.y), to_fp8(v.z), to_fp8(v.w) };
      *(uchar4*)&q8[i][t * 4] = q;
    }
    __syncthreads();
    if (t < 16)
      agr[bid * 16 + t] = dred[0][t] + dred[1][t] + dred[2][t] + dred[3][t];
    unsigned char* dst = t8p + (long)bid * 16384;   // 32 chunks x 512B
    #pragma unroll
    for (int c = 0; c < 8; ++c) {
      int kb = wid * 8 + c;
      uint2 r = *(const uint2*)&q8[lane & 15][kb * 32 + (lane >> 4) * 8];
      *(uint2*)(dst + kb * 512 + lane * 8) = r;     // coalesced 512B/wave
    }
  } else {
    __shared__ float tile[64][65];
    int lb = bid - 1024;
    int hr = (lb >> 4) * 64;
    int ec = (lb & 15) * 64;
    int lr = t >> 4, lc = t & 15;
    #pragma unroll
    for (int rr = 0; rr < 4; ++rr) {
      int r = rr * 16 + lr;
      float4 v = *(const float4*)(Wt + (long)(hr + r) * H_ + ec + lc * 4);
      tile[r][lc * 4 + 0] = v.x; tile[r][lc * 4 + 1] = v.y;
      tile[r][lc * 4 + 2] = v.z; tile[r][lc * 4 + 3] = v.w;
    }
    __syncthreads();
    #pragma unroll
    for (int rr = 0; rr < 4; ++rr) {
      int er = rr * 16 + lr;
      bf16x4 o = { (bf16_t)tile[lc * 4 + 0][er], (bf16_t)tile[lc * 4 + 1][er],
                   (bf16_t)tile[lc * 4 + 2][er], (bf16_t)tile[lc * 4 + 3][er] };
      *(bf16x4*)(WtT + (long)(ec + er) * H_ + hr + lc * 4) = o;
    }
  }
}

// ---- merged: [0,256) Wc8p = frag-packed fp8(16 * Wgt@Wt); [256,264) softmax
__global__ __launch_bounds__(256) void wc_sm(const float* __restrict__ Wg,
                                             const bf16_t* __restrict__ Bt,
                                             unsigned char* __restrict__ Cw8,
                                             const float* __restrict__ ag,
                                             float* __restrict__ r) {
  __shared__ __align__(16) char lds[2][16384];
  __shared__ float red[4];
  if (blockIdx.x >= 256) {
    int b = blockIdx.x - 256, t = threadIdx.x;
    int wid = t >> 6, lane = t & 63;
    const float* a = ag + (long)b * L_;
    float v[8];
    float mx = -1e30f;
    #pragma unroll
    for (int j = 0; j < 8; ++j) { v[j] = 2.f * a[t + 256 * j]; mx = fmaxf(mx, v[j]); }
    for (int off = 32; off; off >>= 1) mx = fmaxf(mx, __shfl_down(mx, off));
    if (!lane) red[wid] = mx;
    __syncthreads();
    mx = fmaxf(fmaxf(red[0], red[1]), fmaxf(red[2], red[3]));
    __syncthreads();
    float sum = 0.f;
    #pragma unroll
    for (int j = 0; j < 8; ++j) { v[j] = __expf(v[j] - mx); sum += v[j]; }
    for (int off = 32; off; off >>= 1) sum += __shfl_down(sum, off);
    if (!lane) red[wid] = sum;
    __syncthreads();
    sum = red[0] + red[1] + red[2] + red[3];
    float inv = 1.f / sum;
    #pragma unroll
    for (int j = 0; j < 8; ++j) r[(long)b * L_ + t + 256 * j] = v[j] * inv;
    return;
  }
  const int tid = threadIdx.x;
  const int wid = tid >> 6, lane = tid & 63;
  const int fr = lane & 15, fkb = (lane >> 4) * 16, fq = (lane >> 4) * 4;
  const int wm = wid >> 1, wn = wid & 1;
  const int tm = blockIdx.x & 15, tn = blockIdx.x >> 4;
  const int m0 = tm * 64, n0 = tn * 64;

  const int d0 = tid * 16;
  const int p  = d0 ^ (((d0 >> 7) & 7) << 4);
  const int rS = p >> 7, cS = (p & 127) >> 1;

  const int swz = (fr & 7) << 4;
  const int e0 = fkb ^ swz;
  const int e1 = (64 + fkb) ^ swz;

  auto stage = [&](int t) {
    char* base = lds[t & 1];
    gload_lds16(base + 8192 + d0,        Bt + (long)(n0 + rS) * H_ + t * 64 + cS);
    gload_lds16(base + 8192 + 4096 + d0, Bt + (long)(n0 + 32 + rS) * H_ + t * 64 + cS);
    const float* a0 = Wg + (long)(m0 + rS) * 2048 + t * 64 + cS;
    const float* a1 = Wg + (long)(m0 + 32 + rS) * 2048 + t * 64 + cS;
    float4 x0 = *(const float4*)a0, x1 = *(const float4*)(a0 + 4);
    float4 y0 = *(const float4*)a1, y1 = *(const float4*)(a1 + 4);
    bf16x8 bx = { (bf16_t)x0.x, (bf16_t)x0.y, (bf16_t)x0.z, (bf16_t)x0.w,
                  (bf16_t)x1.x, (bf16_t)x1.y, (bf16_t)x1.z, (bf16_t)x1.w };
    bf16x8 by = { (bf16_t)y0.x, (bf16_t)y0.y, (bf16_t)y0.z, (bf16_t)y0.w,
                  (bf16_t)y1.x, (bf16_t)y1.y, (bf16_t)y1.z, (bf16_t)y1.w };
    *(bf16x8*)(base + d0) = bx;
    *(bf16x8*)(base + 4096 + d0) = by;
  };

  f32x4 acc[2][2];
  #pragma unroll
  for (int m = 0; m < 2; ++m)
    #pragma unroll
    for (int n = 0; n < 2; ++n) acc[m][n] = (f32x4){0.f, 0.f, 0.f, 0.f};

  stage(0);
  __syncthreads();
  for (int t = 0; t < 16; ++t) {
    if (t + 1 < 16) stage(t + 1);
    char* buf = lds[t & 1];
    char* AR = buf + (wm * 32 + fr) * 128;
    char* BR = buf + 8192 + (wn * 32 + fr) * 128;
    bf16x8 a[2][2], b[2][2];
    #pragma unroll
    for (int m = 0; m < 2; ++m) {
      a[m][0] = *(const bf16x8*)(AR + m * 2048 + e0);
      a[m][1] = *(const bf16x8*)(AR + m * 2048 + e1);
      b[m][0] = *(const bf16x8*)(BR + m * 2048 + e0);
      b[m][1] = *(const bf16x8*)(BR + m * 2048 + e1);
    }
    #pragma unroll
    for (int m = 0; m < 2; ++m)
      #pragma unroll
      for (int n = 0; n < 2; ++n) {
        acc[m][n] = __builtin_amdgcn_mfma_f32_16x16x32_bf16(a[m][0], b[n][0], acc[m][n], 0, 0, 0);
        acc[m][n] = __builtin_amdgcn_mfma_f32_16x16x32_bf16(a[m][1], b[n][1], acc[m][n], 0, 0, 0);
      }
    __syncthreads();
  }
  // frag-packed write: chunk(nb=row>>4, kb=col>>5), lane=(row&15)|(((col>>3)&3)<<4)
  #pragma unroll
  for (int m = 0; m < 2; ++m)
    #pragma unroll
    for (int r_ = 0; r_ < 4; ++r_) {
      int row = m0 + wm * 32 + m * 16 + fq + r_;
      #pragma unroll
      for (int n = 0; n < 2; ++n) {
        int col = n0 + wn * 32 + n * 16 + fr;
        Cw8[((row >> 4) * 32 + (col >> 5)) * 512
            + ((row & 15) + (((col >> 3) & 3) << 4)) * 8 + (col & 7)]
          = to_fp8(acc[m][n][r_] * 16.f);   // x16 into e4m3 normal range
      }
    }
}

// ====== full-row fp8 GEMM + gate/residual + LayerNorm, all in one ==========
// 256 blocks x 64 rows x 1024 cols, 512 thr (8 waves, each 64x128 out).
// 1 block/CU, __launch_bounds__(512,2) -> 256-VGPR budget (R5 spill fix).
// K-step 64 (16 k-tiles): 64 MFMA/wave between sync points (4x R2 density,
// m233 lesson), B bytes per MFMA halved. All staging via global_load_lds,
// uniform 10 issues/thread/tile (2x4B A + 8x16B B); counted vmcnt(10) = 2
// tiles in flight, never drained mid-loop. Frag-packed chunks keep LDS
// linear + conflict-free (ds_read_b64, 64 lanes read 512B contiguous).
// LDS 140KB dyn: A dbuf 2x4K @0, B dbuf 2x64K @8192, LN arrays @139264.
#define BOFF 16777216   // Wc8p offset from t8p base
__global__ __launch_bounds__(512, 2)
void gemm_ln(const unsigned char* __restrict__ AB,
             const float* __restrict__ textf,
             const float* __restrict__ cbb, const float* __restrict__ rbuf,
             const float* __restrict__ gvb, const float* __restrict__ vpb,
             const float* __restrict__ gamma, const float* __restrict__ beta,
             float* __restrict__ out) {
  extern __shared__ __align__(16) char dlds[];
  float* pS  = (float*)(dlds + 139264);   // [64][8]
  float* pQ  = (float*)(dlds + 141312);   // [64][8]
  float* muA = (float*)(dlds + 143360);   // [64]
  float* invA= (float*)(dlds + 143616);   // [64]
  const int tid  = threadIdx.x;
  const int w    = tid >> 6;            // 0..7 col strip (128 cols)
  const int lane = tid & 63;
  const int fr   = lane & 15;
  const int fq   = (lane >> 4) * 4;
  const int bid  = blockIdx.x;
  const long m0  = (long)bid * 64;

  // A stage: 4KB/tile = 2 x gload_lds4 per thread. LDS image chunk-linear:
  // byte o in [0,4096): mbl=o>>10, kbl=(o>>9)&1, intra=o&511.
  const int o0 = w * 256 + lane * 4;
  const int o1 = 2048 + w * 256 + lane * 4;
  const unsigned char* aS0 = AB + (long)bid * 65536 + (o0 >> 10) * 16384
                                + ((o0 >> 9) & 1) * 512 + (o0 & 511);
  const unsigned char* aS1 = AB + (long)bid * 65536 + (o1 >> 10) * 16384
                                + ((o1 >> 9) & 1) * 512 + (o1 & 511);
  // B stage: 64KB/tile = 8 x gload_lds16 per thread; issue r covers nb=r*8+w,
  // 1KB contiguous (chunks kb=2t,2t+1 adjacent in global).
  const unsigned char* bS = AB + BOFF + (long)w * 16384 + lane * 16;

  f32x4 acc[4][8];
  #pragma unroll
  for (int m = 0; m < 4; ++m)
    #pragma unroll
    for (int n = 0; n < 8; ++n) acc[m][n] = (f32x4){0.f, 0.f, 0.f, 0.f};

#define STAGE(t)                                                        \
  {                                                                     \
    gload_lds4(dlds + ((t) & 1) * 4096 + o0, aS0 + (t) * 1024);         \
    gload_lds4(dlds + ((t) & 1) * 4096 + o1, aS1 + (t) * 1024);         \
    _Pragma("unroll")                                                   \
    for (int r_ = 0; r_ < 8; ++r_)                                      \
      gload_lds16(dlds + 8192 + ((t) & 1) * 65536 + (r_ * 8 + w) * 1024 \
                       + lane * 16,                                     \
                  bS + (long)r_ * 131072 + (t) * 1024);                 \
  }
#define KITER(t, WN, DOSTAGE)                                           \
  {                                                                     \
    asm volatile("s_waitcnt vmcnt(" #WN ")" ::: "memory");              \
    __builtin_amdgcn_s_barrier();                                       \
    const char* Ab_ = dlds + ((t) & 1) * 4096 + lane * 8;               \
    const char* Bb_ = dlds + 8192 + ((t) & 1) * 65536 + w * 8192        \
                           + lane * 8;                                  \
    long a_[4][2], b_[8][2];                                            \
    _Pragma("unroll")                                                   \
    for (int m_ = 0; m_ < 4; ++m_) {                                    \
      a_[m_][0] = *(const long*)(Ab_ + m_ * 1024);                      \
      a_[m_][1] = *(const long*)(Ab_ + m_ * 1024 + 512);                \
    }                                                                   \
    _Pragma("unroll")                                                   \
    for (int n_ = 0; n_ < 8; ++n_) {                                    \
      b_[n_][0] = *(const long*)(Bb_ + n_ * 1024);                      \
      b_[n_][1] = *(const long*)(Bb_ + n_ * 1024 + 512);                \
    }                                                                   \
    asm volatile("s_waitcnt lgkmcnt(0)" ::: "memory");                  \
    __builtin_amdgcn_sched_barrier(0);                                  \
    __builtin_amdgcn_s_barrier();                                       \
    if (DOSTAGE) STAGE((t) + 2)                                         \
    __builtin_amdgcn_s_setprio(1);                                      \
    _Pragma("unroll")                                                   \
    for (int m_ = 0; m_ < 4; ++m_)                                      \
      _Pragma("unroll")                                                 \
      for (int n_ = 0; n_ < 8; ++n_)                                    \
        _Pragma("unroll")                                               \
        for (int k_ = 0; k_ < 2; ++k_)                                  \
          acc[m_][n_] = __builtin_amdgcn_mfma_f32_16x16x32_fp8_fp8(     \
              a_[m_][k_], b_[n_][k_], acc[m_][n_], 0, 0, 0);            \
    __builtin_amdgcn_s_setprio(0);                                      \
  }

  STAGE(0)
  asm volatile("" ::: "memory");
  STAGE(1)

  KITER(0, 10, true)  KITER(1, 10, true)  KITER(2, 10, true)
  KITER(3, 10, true)  KITER(4, 10, true)  KITER(5, 10, true)
  KITER(6, 10, true)  KITER(7, 10, true)  KITER(8, 10, true)
  KITER(9, 10, true)  KITER(10, 10, true) KITER(11, 10, true)
  KITER(12, 10, true) KITER(13, 10, true)
  KITER(14, 10, false)
  KITER(15, 0, false)
#undef KITER
#undef STAGE

  // ---- epilogue: gate + residual in fp32, then LayerNorm, write out -------
  // (R2's proven no-spill scattered form; 256-VGPR budget here.)
  const int bat = (int)(m0 >> 11);
  const float* gvr = gvb + bat * H_;
  const float* vpr = vpb + bat * H_;
  float cb_[8], gv_[8], vp_[8];
  #pragma unroll
  for (int n = 0; n < 8; ++n) {
    int col = w * 128 + n * 16 + fr;
    cb_[n] = cbb[col]; gv_[n] = gvr[col]; vp_[n] = vpr[col];
  }
  #pragma unroll
  for (int m = 0; m < 4; ++m) {
    #pragma unroll
    for (int r = 0; r < 4; ++r) {
      int rl = m * 16 + fq + r;
      long row = m0 + rl;
      const float rv = rbuf[row];
      const float* tf = textf + row * H_;
      float s = 0.f, q = 0.f;
      #pragma unroll
      for (int n = 0; n < 8; ++n) {
        int col = w * 128 + n * 16 + fr;
        float gp = acc[m][n][r] * 0.0625f + cb_[n] + rv * gv_[n];
        float g = 1.f / (1.f + __expf(-gp));
        float f = tf[col] + g * rv * vp_[n];
        acc[m][n][r] = f;                 // acc now holds fused (fp32)
        s += f; q += f * f;
      }
      #pragma unroll
      for (int off = 1; off < 16; off <<= 1) {   // reduce over 16-lane group
        s += __shfl_xor(s, off);
        q += __shfl_xor(q, off);
      }
      if (fr == 0) {
        pS[rl * 8 + w] = s;
        pQ[rl * 8 + w] = q;
      }
    }
  }
  __syncthreads();
  if (tid < 64) {
    float S = 0.f, Q = 0.f;
    #pragma unroll
    for (int w2 = 0; w2 < 8; ++w2) { S += pS[tid * 8 + w2]; Q += pQ[tid * 8 + w2]; }
    float mu = S * (1.f / H_);
    float var = Q * (1.f / H_) - mu * mu;
    muA[tid] = mu;
    invA[tid] = rsqrtf(var + 1e-5f);
  }
  __syncthreads();
  #pragma unroll
  for (int m = 0; m < 4; ++m) {
    #pragma unroll
    for (int r = 0; r < 4; ++r) {
      int rl = m * 16 + fq + r;
      float mu = muA[rl], inv = invA[rl];
      float* op = out + (m0 + rl) * H_;
      #pragma unroll
      for (int n = 0; n < 8; ++n) {
        int col = w * 128 + n * 16 + fr;
        op[col] = (acc[m][n][r] - mu) * inv * gamma[col] + beta[col];
      }
    }
  }
}

extern "C" void kernel_launch(void* const* d_in, const int* in_sizes, int n_in,
                              void* d_out, int out_size, void* d_ws, size_t ws_size,
                              hipStream_t stream) {
  const float* text  = (const float*)d_in[0];
  const float* vis   = (const float*)d_in[1];
  const float* Wt    = (const float*)d_in[2];
  const float* bt    = (const float*)d_in[3];
  const float* Wv    = (const float*)d_in[4];
  const float* bv    = (const float*)d_in[5];
  const float* Wg    = (const float*)d_in[6];
  const float* bg    = (const float*)d_in[7];
  const float* gamma = (const float*)d_in[8];
  const float* beta  = (const float*)d_in[9];
  float* out = (float*)d_out;

  char* ws = (char*)d_ws;
  unsigned char* t8p   = (unsigned char*)(ws);                    // 16 MiB (packed A)
  unsigned char* Wc8p  = (unsigned char*)(ws + (size_t)16777216); // 1 MiB (packed B)
  bf16_t* WtT_b = (bf16_t*)(ws + (size_t)17825792);               // 2 MiB
  float*  pooled = (float*)(ws + (size_t)19922944);               // 32 KiB
  float*  vp     = (float*)(ws + (size_t)19955712);               // 32 KiB
  float*  gv     = (float*)(ws + (size_t)19988480);               // 32 KiB
  float*  u      = (float*)(ws + (size_t)20021248);               // 32 KiB
  float*  cbb    = (float*)(ws + (size_t)20054016);               // 4 KiB
  float*  rbuf   = (float*)(ws + (size_t)20058112);               // 64 KiB
  float*  agr    = (float*)(ws + (size_t)20123648);               // 64 KiB
  float*  partU  = (float*)(ws + (size_t)20189184);               // 2 MiB

  static bool smem_set = false;
  if (!smem_set) {
    (void)hipFuncSetAttribute((const void*)gemm_ln,
                              hipFuncAttributeMaxDynamicSharedMemorySize, 143872);
    smem_set = true;
  }

  vpool64<<<64, 256, 0, stream>>>(vis, pooled);                   // mean-pool
  matvec8<<<256, 256, 0, stream>>>(Wv, 1024, 0, pooled, bv, vp);  // vp
  smallops<<<768, 256, 0, stream>>>(Wg, Wt, vp, bt, bg, gv, partU, cbb);
  reduceK<<<32, 256, 0, stream>>>(partU, u, 64, 1.f);             // u = Wt^T vp

  cvt_pack<<<1280, 256, 0, stream>>>(text, u, Wt, t8p, agr, WtT_b);
  wc_sm<<<264, 256, 0, stream>>>(Wg, WtT_b, Wc8p, agr, rbuf);     // Wc8p + softmax

  gemm_ln<<<256, 512, 143872, stream>>>(t8p, text, cbb, rbuf, gv, vp,
                                        gamma, beta, out);
}

// Round 7
// 120.974 us; speedup vs baseline: 2.5307x; 1.0350x over previous
//
#include <hip/hip_runtime.h>
#include <hip/hip_bf16.h>
#include <hip/hip_fp8.h>

typedef __bf16 bf16_t;
typedef bf16_t bf16x4 __attribute__((ext_vector_type(4)));
typedef bf16_t bf16x8 __attribute__((ext_vector_type(8)));
typedef float  f32x4  __attribute__((ext_vector_type(4)));

#define B_  8
#define L_  2048
#define H_  1024
#define LV_ 256

typedef const __attribute__((address_space(1))) void* gptr_as1;
typedef __attribute__((address_space(3))) void* lptr_as3;

__device__ __forceinline__ void gload_lds16(void* lds_base, const void* gsrc) {
  __builtin_amdgcn_global_load_lds((gptr_as1)gsrc, (lptr_as3)lds_base, 16, 0, 0);
}
__device__ __forceinline__ void gload_lds4(void* lds_base, const void* gsrc) {
  __builtin_amdgcn_global_load_lds((gptr_as1)gsrc, (lptr_as3)lds_base, 4, 0, 0);
}

__device__ __forceinline__ unsigned char to_fp8(float x) {
  return __hip_fp8_e4m3(x).__x;
}

// ---- vision mean-pool: 64 blocks, 2-way k-split, LDS combine ---------------
__global__ __launch_bounds__(256) void vpool64(const float* __restrict__ vf,
                                               float* __restrict__ pooled) {
  __shared__ float part[256];
  int bid = blockIdx.x;                 // b(8) x hc(8)
  int b = bid >> 3, hc = bid & 7;
  int t = threadIdx.x;
  int h = hc * 128 + (t & 127);
  int kh = t >> 7;
  const float* p = vf + (long)b * (LV_ * H_) + (long)kh * 128 * H_ + h;
  float s = 0.f;
  #pragma unroll 4
  for (int k = 0; k < 128; ++k) s += p[k * H_];
  part[t] = s;
  __syncthreads();
  if (t < 128)
    pooled[b * H_ + hc * 128 + t] = (part[t] + part[t + 128]) * (1.f / 256.f);
}

// ------- out[b][o] = sum_h x[b][h]*W[o*ldw+woff+h] (+bias), 8 batches ------
__global__ void matvec8(const float* __restrict__ W, int ldw, int woff,
                        const float* __restrict__ x,
                        const float* __restrict__ bias,
                        float* __restrict__ out) {
  int wid = threadIdx.x >> 6, lane = threadIdx.x & 63;
  int o = blockIdx.x * 4 + wid;
  const float* wr = W + (long)o * ldw + woff;
  float acc[B_];
  #pragma unroll
  for (int b = 0; b < B_; ++b) acc[b] = 0.f;
  for (int j = 0; j < 16; ++j) {
    float w = wr[lane + 64 * j];
    #pragma unroll
    for (int b = 0; b < B_; ++b) acc[b] += w * x[b * H_ + lane + 64 * j];
  }
  #pragma unroll
  for (int b = 0; b < B_; ++b)
    for (int off = 32; off; off >>= 1) acc[b] += __shfl_down(acc[b], off);
  if (lane == 0) {
    float bb = bias ? bias[o] : 0.f;
    #pragma unroll
    for (int b = 0; b < B_; ++b) out[b * H_ + o] = acc[b] + bb;
  }
}

// ---- fused small ops (all read-only on vp): 768 blocks ---------------------
__global__ __launch_bounds__(256) void smallops(const float* __restrict__ Wg,
                                                const float* __restrict__ Wt,
                                                const float* __restrict__ vp,
                                                const float* __restrict__ bt,
                                                const float* __restrict__ bg,
                                                float* __restrict__ gv,
                                                float* __restrict__ partU,
                                                float* __restrict__ cbb) {
  int bid = blockIdx.x;
  if (bid < 256) {
    int wid = threadIdx.x >> 6, lane = threadIdx.x & 63;
    int o = bid * 4 + wid;
    const float* wr = Wg + (long)o * 2048 + 1024;
    float acc[B_];
    #pragma unroll
    for (int b = 0; b < B_; ++b) acc[b] = 0.f;
    for (int j = 0; j < 16; ++j) {
      float w = wr[lane + 64 * j];
      #pragma unroll
      for (int b = 0; b < B_; ++b) acc[b] += w * vp[b * H_ + lane + 64 * j];
    }
    #pragma unroll
    for (int b = 0; b < B_; ++b)
      for (int off = 32; off; off >>= 1) acc[b] += __shfl_down(acc[b], off);
    if (lane == 0) {
      #pragma unroll
      for (int b = 0; b < B_; ++b) gv[b * H_ + o] = acc[b];
    }
  } else if (bid < 512) {
    int lb = bid - 256;                 // eb(4) x oc(64)
    int e = (lb & 3) * 256 + threadIdx.x;
    int oc = lb >> 2;
    float a[B_];
    #pragma unroll
    for (int b = 0; b < B_; ++b) a[b] = 0.f;
    #pragma unroll
    for (int i = 0; i < 16; ++i) {
      int o = oc * 16 + i;
      float w = Wt[(long)o * H_ + e];
      #pragma unroll
      for (int b = 0; b < B_; ++b) a[b] += w * vp[b * H_ + o];
    }
    #pragma unroll
    for (int b = 0; b < B_; ++b) partU[oc * 8192 + b * 1024 + e] = a[b];
  } else {
    int lb = bid - 512;
    int wid = threadIdx.x >> 6, lane = threadIdx.x & 63;
    int o = lb * 4 + wid;
    const float* wr = Wg + (long)o * 2048;
    float acc = 0.f;
    for (int j = 0; j < 16; ++j) acc += wr[lane + 64 * j] * bt[lane + 64 * j];
    for (int off = 32; off; off >>= 1) acc += __shfl_down(acc, off);
    if (lane == 0) cbb[o] = acc + bg[o];
  }
}

// ---- dst[j] = scale * sum_{c<nc} src[c*8192 + j], j < 8192 ----------------
__global__ __launch_bounds__(256) void reduceK(const float* __restrict__ src,
                                               float* __restrict__ dst,
                                               int nc, float scale) {
  int j = blockIdx.x * 256 + threadIdx.x;
  float s = 0.f;
  for (int c = 0; c < nc; ++c) s += src[c * 8192 + j];
  dst[j] = s * scale;
}

// ---- merged: [0,1024) text -> fp8 FRAG-PACKED + agreement dot;
//      [1024,1280) Wt transpose-convert -----------------------------------
// Packed layout: chunk(mb,kb) @ (mb*32+kb)*512; lane l byte j holds
// fp8(text[mb*16 + (l&15)][kb*32 + (l>>4)*8 + j]) -- exact MFMA A/B operand
// order for 16x16x32 fp8.
__global__ __launch_bounds__(256) void cvt_pack(const float* __restrict__ text,
                                                const float* __restrict__ u,
                                                const float* __restrict__ Wt,
                                                unsigned char* __restrict__ t8p,
                                                float* __restrict__ agr,
                                                bf16_t* __restrict__ WtT) {
  int bid = blockIdx.x;
  int t = threadIdx.x;
  if (bid < 1024) {
    __shared__ unsigned char q8[16][1032];   // +8B row pad: frag-read conflicts <=4-way
    __shared__ float dred[4][16];
    int b = bid >> 7;                        // 128 blocks per batch
    int wid = t >> 6, lane = t & 63;
    const float4* trow = (const float4*)(text + (long)bid * (16 * H_));
    float4 uu = ((const float4*)(u + b * H_))[t];
    #pragma unroll 4
    for (int i = 0; i < 16; ++i) {           // i = row within 16-row block
      float4 v = trow[i * 256 + t];          // coalesced
      float d = v.x * uu.x + v.y * uu.y + v.z * uu.z + v.w * uu.w;
      for (int off = 32; off; off >>= 1) d += __shfl_down(d, off);
      if (!lane) dred[wid][i] = d;
      uchar4 q = { to_fp8(v.x), to_fp8(v.y), to_fp8(v.z), to_fp8(v.w) };
      *(uchar4*)&q8[i][t * 4] = q;
    }
    __syncthreads();
    if (t < 16)
      agr[bid * 16 + t] = dred[0][t] + dred[1][t] + dred[2][t] + dred[3][t];
    unsigned char* dst = t8p + (long)bid * 16384;   // 32 chunks x 512B
    #pragma unroll
    for (int c = 0; c < 8; ++c) {
      int kb = wid * 8 + c;
      uint2 r = *(const uint2*)&q8[lane & 15][kb * 32 + (lane >> 4) * 8];
      *(uint2*)(dst + kb * 512 + lane * 8) = r;     // coalesced 512B/wave
    }
  } else {
    __shared__ float tile[64][65];
    int lb = bid - 1024;
    int hr = (lb >> 4) * 64;
    int ec = (lb & 15) * 64;
    int lr = t >> 4, lc = t & 15;
    #pragma unroll
    for (int rr = 0; rr < 4; ++rr) {
      int r = rr * 16 + lr;
      float4 v = *(const float4*)(Wt + (long)(hr + r) * H_ + ec + lc * 4);
      tile[r][lc * 4 + 0] = v.x; tile[r][lc * 4 + 1] = v.y;
      tile[r][lc * 4 + 2] = v.z; tile[r][lc * 4 + 3] = v.w;
    }
    __syncthreads();
    #pragma unroll
    for (int rr = 0; rr < 4; ++rr) {
      int er = rr * 16 + lr;
      bf16x4 o = { (bf16_t)tile[lc * 4 + 0][er], (bf16_t)tile[lc * 4 + 1][er],
                   (bf16_t)tile[lc * 4 + 2][er], (bf16_t)tile[lc * 4 + 3][er] };
      *(bf16x4*)(WtT + (long)(ec + er) * H_ + hr + lc * 4) = o;
    }
  }
}

// ---- merged: [0,256) Wc8p = frag-packed fp8(16 * Wgt@Wt); [256,264) softmax
__global__ __launch_bounds__(256) void wc_sm(const float* __restrict__ Wg,
                                             const bf16_t* __restrict__ Bt,
                                             unsigned char* __restrict__ Cw8,
                                             const float* __restrict__ ag,
                                             float* __restrict__ r) {
  __shared__ __align__(16) char lds[2][16384];
  __shared__ float red[4];
  if (blockIdx.x >= 256) {
    int b = blockIdx.x - 256, t = threadIdx.x;
    int wid = t >> 6, lane = t & 63;
    const float* a = ag + (long)b * L_;
    float v[8];
    float mx = -1e30f;
    #pragma unroll
    for (int j = 0; j < 8; ++j) { v[j] = 2.f * a[t + 256 * j]; mx = fmaxf(mx, v[j]); }
    for (int off = 32; off; off >>= 1) mx = fmaxf(mx, __shfl_down(mx, off));
    if (!lane) red[wid] = mx;
    __syncthreads();
    mx = fmaxf(fmaxf(red[0], red[1]), fmaxf(red[2], red[3]));
    __syncthreads();
    float sum = 0.f;
    #pragma unroll
    for (int j = 0; j < 8; ++j) { v[j] = __expf(v[j] - mx); sum += v[j]; }
    for (int off = 32; off; off >>= 1) sum += __shfl_down(sum, off);
    if (!lane) red[wid] = sum;
    __syncthreads();
    sum = red[0] + red[1] + red[2] + red[3];
    float inv = 1.f / sum;
    #pragma unroll
    for (int j = 0; j < 8; ++j) r[(long)b * L_ + t + 256 * j] = v[j] * inv;
    return;
  }
  const int tid = threadIdx.x;
  const int wid = tid >> 6, lane = tid & 63;
  const int fr = lane & 15, fkb = (lane >> 4) * 16, fq = (lane >> 4) * 4;
  const int wm = wid >> 1, wn = wid & 1;
  const int tm = blockIdx.x & 15, tn = blockIdx.x >> 4;
  const int m0 = tm * 64, n0 = tn * 64;

  const int d0 = tid * 16;
  const int p  = d0 ^ (((d0 >> 7) & 7) << 4);
  const int rS = p >> 7, cS = (p & 127) >> 1;

  const int swz = (fr & 7) << 4;
  const int e0 = fkb ^ swz;
  const int e1 = (64 + fkb) ^ swz;

  auto stage = [&](int t) {
    char* base = lds[t & 1];
    gload_lds16(base + 8192 + d0,        Bt + (long)(n0 + rS) * H_ + t * 64 + cS);
    gload_lds16(base + 8192 + 4096 + d0, Bt + (long)(n0 + 32 + rS) * H_ + t * 64 + cS);
    const float* a0 = Wg + (long)(m0 + rS) * 2048 + t * 64 + cS;
    const float* a1 = Wg + (long)(m0 + 32 + rS) * 2048 + t * 64 + cS;
    float4 x0 = *(const float4*)a0, x1 = *(const float4*)(a0 + 4);
    float4 y0 = *(const float4*)a1, y1 = *(const float4*)(a1 + 4);
    bf16x8 bx = { (bf16_t)x0.x, (bf16_t)x0.y, (bf16_t)x0.z, (bf16_t)x0.w,
                  (bf16_t)x1.x, (bf16_t)x1.y, (bf16_t)x1.z, (bf16_t)x1.w };
    bf16x8 by = { (bf16_t)y0.x, (bf16_t)y0.y, (bf16_t)y0.z, (bf16_t)y0.w,
                  (bf16_t)y1.x, (bf16_t)y1.y, (bf16_t)y1.z, (bf16_t)y1.w };
    *(bf16x8*)(base + d0) = bx;
    *(bf16x8*)(base + 4096 + d0) = by;
  };

  f32x4 acc[2][2];
  #pragma unroll
  for (int m = 0; m < 2; ++m)
    #pragma unroll
    for (int n = 0; n < 2; ++n) acc[m][n] = (f32x4){0.f, 0.f, 0.f, 0.f};

  stage(0);
  __syncthreads();
  for (int t = 0; t < 16; ++t) {
    if (t + 1 < 16) stage(t + 1);
    char* buf = lds[t & 1];
    char* AR = buf + (wm * 32 + fr) * 128;
    char* BR = buf + 8192 + (wn * 32 + fr) * 128;
    bf16x8 a[2][2], b[2][2];
    #pragma unroll
    for (int m = 0; m < 2; ++m) {
      a[m][0] = *(const bf16x8*)(AR + m * 2048 + e0);
      a[m][1] = *(const bf16x8*)(AR + m * 2048 + e1);
      b[m][0] = *(const bf16x8*)(BR + m * 2048 + e0);
      b[m][1] = *(const bf16x8*)(BR + m * 2048 + e1);
    }
    #pragma unroll
    for (int m = 0; m < 2; ++m)
      #pragma unroll
      for (int n = 0; n < 2; ++n) {
        acc[m][n] = __builtin_amdgcn_mfma_f32_16x16x32_bf16(a[m][0], b[n][0], acc[m][n], 0, 0, 0);
        acc[m][n] = __builtin_amdgcn_mfma_f32_16x16x32_bf16(a[m][1], b[n][1], acc[m][n], 0, 0, 0);
      }
    __syncthreads();
  }
  // frag-packed write: chunk(nb=row>>4, kb=col>>5), lane=(row&15)|(((col>>3)&3)<<4)
  #pragma unroll
  for (int m = 0; m < 2; ++m)
    #pragma unroll
    for (int r_ = 0; r_ < 4; ++r_) {
      int row = m0 + wm * 32 + m * 16 + fq + r_;
      #pragma unroll
      for (int n = 0; n < 2; ++n) {
        int col = n0 + wn * 32 + n * 16 + fr;
        Cw8[((row >> 4) * 32 + (col >> 5)) * 512
            + ((row & 15) + (((col >> 3) & 3) << 4)) * 8 + (col & 7)]
          = to_fp8(acc[m][n][r_] * 16.f);   // x16 into e4m3 normal range
      }
    }
}

// ====== full-row fp8 GEMM + gate/residual + LayerNorm, all in one ==========
// 256 blocks x 64 rows x 1024 cols, 512 thr (8 waves, each 64x128 out).
// K-step 32, 32 tiles, *** 3-deep LDS rotation *** (A 3x2K + B 3x32K=102K):
// stage(t+2) never touches the buffer tile t reads, so NO mid-tile
// lgkmcnt(0)/second-barrier -- compiler interleaves 12 ds_read_b64 with
// 32 MFMA via fine counted lgkm waits (m97 behavior). Per tile only:
// sched_bar | vmcnt(5) | s_barrier | sched_bar | 5 DMA issues | reads+MFMA.
// vmcnt BEFORE barrier makes cross-wave staging safe (each wave drains its
// own tile-t DMAs, barrier joins all). sched_barrier(0) blocks rule-#18
// MFMA hoist/sink races at tile boundaries.
#define BOFF 16777216   // Wc8p offset from t8p base
__global__ __launch_bounds__(512, 2)
void gemm_ln(const unsigned char* __restrict__ AB,
             const float* __restrict__ textf,
             const float* __restrict__ cbb, const float* __restrict__ rbuf,
             const float* __restrict__ gvb, const float* __restrict__ vpb,
             const float* __restrict__ gamma, const float* __restrict__ beta,
             float* __restrict__ out) {
  extern __shared__ __align__(16) char dlds[];
  // A bufs @0 (3x2048), B bufs @6144 (3x32768), LN scratch @104448
  float* pS  = (float*)(dlds + 104448);   // [64][8]
  float* pQ  = (float*)(dlds + 106496);   // [64][8]
  float* muA = (float*)(dlds + 108544);   // [64]
  float* invA= (float*)(dlds + 108800);   // [64]
  const int tid  = threadIdx.x;
  const int w    = tid >> 6;            // 0..7 col strip (128 cols)
  const int lane = tid & 63;
  const int fr   = lane & 15;
  const int fq   = (lane >> 4) * 4;
  const int bid  = blockIdx.x;
  const long m0  = (long)bid * 64;

  // A stage: 2KB/tile, 1 x gload_lds4/thread, chunk-linear LDS image.
  const int o0 = tid * 4;
  const unsigned char* aSrc = AB + (long)bid * 65536 + (o0 >> 9) * 16384 + (o0 & 511);
  // B stage: 32KB/tile, 4 x gload_lds16/thread; issue r covers nb=r*16+(tid>>5).
  const unsigned char* bSrc = AB + BOFF + (long)(tid >> 5) * 16384 + (tid & 31) * 16;
  const int bD = (tid >> 5) * 512 + (tid & 31) * 16;

  f32x4 acc[4][8];
  #pragma unroll
  for (int m = 0; m < 4; ++m)
    #pragma unroll
    for (int n = 0; n < 8; ++n) acc[m][n] = (f32x4){0.f, 0.f, 0.f, 0.f};

#define STAGE(t)                                                        \
  {                                                                     \
    gload_lds4(dlds + ((t) % 3) * 2048 + o0, aSrc + (t) * 512);         \
    _Pragma("unroll")                                                   \
    for (int r_ = 0; r_ < 4; ++r_)                                      \
      gload_lds16(dlds + 6144 + ((t) % 3) * 32768 + r_ * 8192 + bD,     \
                  bSrc + (long)r_ * 262144 + (t) * 512);                \
  }
#define KITER(t, WN)                                                    \
  {                                                                     \
    __builtin_amdgcn_sched_barrier(0);                                  \
    asm volatile("s_waitcnt vmcnt(" #WN ")" ::: "memory");              \
    __builtin_amdgcn_s_barrier();                                       \
    __builtin_amdgcn_sched_barrier(0);                                  \
    if ((t) + 2 < 32) STAGE((t) + 2)                                    \
    const char* Ab_ = dlds + ((t) % 3) * 2048 + lane * 8;               \
    const char* Bb_ = dlds + 6144 + ((t) % 3) * 32768 + w * 4096        \
                           + lane * 8;                                  \
    long a_[4], b_[8];                                                  \
    _Pragma("unroll")                                                   \
    for (int m_ = 0; m_ < 4; ++m_)                                      \
      a_[m_] = *(const long*)(Ab_ + m_ * 512);                          \
    _Pragma("unroll")                                                   \
    for (int n_ = 0; n_ < 8; ++n_)                                      \
      b_[n_] = *(const long*)(Bb_ + n_ * 512);                          \
    _Pragma("unroll")                                                   \
    for (int m_ = 0; m_ < 4; ++m_)                                      \
      _Pragma("unroll")                                                 \
      for (int n_ = 0; n_ < 8; ++n_)                                    \
        acc[m_][n_] = __builtin_amdgcn_mfma_f32_16x16x32_fp8_fp8(       \
            a_[m_], b_[n_], acc[m_][n_], 0, 0, 0);                      \
  }

  STAGE(0)
  asm volatile("" ::: "memory");
  STAGE(1)

  KITER(0, 5)  KITER(1, 5)  KITER(2, 5)  KITER(3, 5)
  KITER(4, 5)  KITER(5, 5)  KITER(6, 5)  KITER(7, 5)
  KITER(8, 5)  KITER(9, 5)  KITER(10, 5) KITER(11, 5)
  KITER(12, 5) KITER(13, 5) KITER(14, 5) KITER(15, 5)
  KITER(16, 5) KITER(17, 5) KITER(18, 5) KITER(19, 5)
  KITER(20, 5) KITER(21, 5) KITER(22, 5) KITER(23, 5)
  KITER(24, 5) KITER(25, 5) KITER(26, 5) KITER(27, 5)
  KITER(28, 5) KITER(29, 5) KITER(30, 5) KITER(31, 0)
#undef KITER
#undef STAGE

  // ---- epilogue: gate + residual in fp32, then LayerNorm, write out -------
  // (R6's proven no-spill scattered form.)
  const int bat = (int)(m0 >> 11);
  const float* gvr = gvb + bat * H_;
  const float* vpr = vpb + bat * H_;
  float cb_[8], gv_[8], vp_[8];
  #pragma unroll
  for (int n = 0; n < 8; ++n) {
    int col = w * 128 + n * 16 + fr;
    cb_[n] = cbb[col]; gv_[n] = gvr[col]; vp_[n] = vpr[col];
  }
  #pragma unroll
  for (int m = 0; m < 4; ++m) {
    #pragma unroll
    for (int r = 0; r < 4; ++r) {
      int rl = m * 16 + fq + r;
      long row = m0 + rl;
      const float rv = rbuf[row];
      const float* tf = textf + row * H_;
      float s = 0.f, q = 0.f;
      #pragma unroll
      for (int n = 0; n < 8; ++n) {
        int col = w * 128 + n * 16 + fr;
        float gp = acc[m][n][r] * 0.0625f + cb_[n] + rv * gv_[n];
        float g = 1.f / (1.f + __expf(-gp));
        float f = tf[col] + g * rv * vp_[n];
        acc[m][n][r] = f;                 // acc now holds fused (fp32)
        s += f; q += f * f;
      }
      #pragma unroll
      for (int off = 1; off < 16; off <<= 1) {   // reduce over 16-lane group
        s += __shfl_xor(s, off);
        q += __shfl_xor(q, off);
      }
      if (fr == 0) {
        pS[rl * 8 + w] = s;
        pQ[rl * 8 + w] = q;
      }
    }
  }
  __syncthreads();
  if (tid < 64) {
    float S = 0.f, Q = 0.f;
    #pragma unroll
    for (int w2 = 0; w2 < 8; ++w2) { S += pS[tid * 8 + w2]; Q += pQ[tid * 8 + w2]; }
    float mu = S * (1.f / H_);
    float var = Q * (1.f / H_) - mu * mu;
    muA[tid] = mu;
    invA[tid] = rsqrtf(var + 1e-5f);
  }
  __syncthreads();
  #pragma unroll
  for (int m = 0; m < 4; ++m) {
    #pragma unroll
    for (int r = 0; r < 4; ++r) {
      int rl = m * 16 + fq + r;
      float mu = muA[rl], inv = invA[rl];
      float* op = out + (m0 + rl) * H_;
      #pragma unroll
      for (int n = 0; n < 8; ++n) {
        int col = w * 128 + n * 16 + fr;
        op[col] = (acc[m][n][r] - mu) * inv * gamma[col] + beta[col];
      }
    }
  }
}

extern "C" void kernel_launch(void* const* d_in, const int* in_sizes, int n_in,
                              void* d_out, int out_size, void* d_ws, size_t ws_size,
                              hipStream_t stream) {
  const float* text  = (const float*)d_in[0];
  const float* vis   = (const float*)d_in[1];
  const float* Wt    = (const float*)d_in[2];
  const float* bt    = (const float*)d_in[3];
  const float* Wv    = (const float*)d_in[4];
  const float* bv    = (const float*)d_in[5];
  const float* Wg    = (const float*)d_in[6];
  const float* bg    = (const float*)d_in[7];
  const float* gamma = (const float*)d_in[8];
  const float* beta  = (const float*)d_in[9];
  float* out = (float*)d_out;

  char* ws = (char*)d_ws;
  unsigned char* t8p   = (unsigned char*)(ws);                    // 16 MiB (packed A)
  unsigned char* Wc8p  = (unsigned char*)(ws + (size_t)16777216); // 1 MiB (packed B)
  bf16_t* WtT_b = (bf16_t*)(ws + (size_t)17825792);               // 2 MiB
  float*  pooled = (float*)(ws + (size_t)19922944);               // 32 KiB
  float*  vp     = (float*)(ws + (size_t)19955712);               // 32 KiB
  float*  gv     = (float*)(ws + (size_t)19988480);               // 32 KiB
  float*  u      = (float*)(ws + (size_t)20021248);               // 32 KiB
  float*  cbb    = (float*)(ws + (size_t)20054016);               // 4 KiB
  float*  rbuf   = (float*)(ws + (size_t)20058112);               // 64 KiB
  float*  agr    = (float*)(ws + (size_t)20123648);               // 64 KiB
  float*  partU  = (float*)(ws + (size_t)20189184);               // 2 MiB

  static bool smem_set = false;
  if (!smem_set) {
    (void)hipFuncSetAttribute((const void*)gemm_ln,
                              hipFuncAttributeMaxDynamicSharedMemorySize, 109056);
    smem_set = true;
  }

  vpool64<<<64, 256, 0, stream>>>(vis, pooled);                   // mean-pool
  matvec8<<<256, 256, 0, stream>>>(Wv, 1024, 0, pooled, bv, vp);  // vp
  smallops<<<768, 256, 0, stream>>>(Wg, Wt, vp, bt, bg, gv, partU, cbb);
  reduceK<<<32, 256, 0, stream>>>(partU, u, 64, 1.f);             // u = Wt^T vp

  cvt_pack<<<1280, 256, 0, stream>>>(text, u, Wt, t8p, agr, WtT_b);
  wc_sm<<<264, 256, 0, stream>>>(Wg, WtT_b, Wc8p, agr, rbuf);     // Wc8p + softmax

  gemm_ln<<<256, 512, 109056, stream>>>(t8p, text, cbb, rbuf, gv, vp,
                                        gamma, beta, out);
}